// Round 15
// baseline (91.214 us; speedup 1.0000x reference)
//
#include <hip/hip_runtime.h>
#include <math.h>

#define DIM   2048
#define NEXP  64
#define TPB   512
#define TOKB  32
#define NCH   64          // ksteps (K=32 each)
#define DEPTH 4
#define SLOTB 16384       // ring slot bytes: 4KB x-frags + 12KB B-frags

typedef float f32x4  __attribute__((ext_vector_type(4)));
typedef short bf16x8 __attribute__((ext_vector_type(8)));
typedef unsigned short u16;

#define MFMA __builtin_amdgcn_mfma_f32_16x16x32_bf16

// ---- fp32 -> 3-term bf16 split (RNE). Error ~2^-26 relative: index-safe. ----
__device__ __forceinline__ u16 rne_bf16(float f) {
    union { float f; unsigned u; } v; v.f = f;
    unsigned u = v.u;
    u += 0x7fffu + ((u >> 16) & 1u);
    return (u16)(u >> 16);
}
__device__ __forceinline__ float bf2f(u16 h) {
    union { unsigned u; float f; } v; v.u = ((unsigned)h) << 16;
    return v.f;
}
__device__ __forceinline__ void split3(float x, u16& a, u16& b, u16& c) {
    a = rne_bf16(x);
    float r1 = x - bf2f(a);
    b = rne_bf16(r1);
    float r2 = r1 - bf2f(b);
    c = rne_bf16(r2);
}

#define GLD(GP, LP) __builtin_amdgcn_global_load_lds(                          \
        (const __attribute__((address_space(1))) unsigned*)(GP),               \
        (__attribute__((address_space(3))) unsigned*)(LP), 16, 0, 0)

// ---------------- Kernel 0: W -> 3 bf16 planes, MFMA-B-fragment-linear -------
// wp[(kstep*4 + etile)*3 + plane][lane][8];
// element: W[16*etile + (lane&15)][32*kstep + 8*(lane>>4) + i]
__global__ __launch_bounds__(256)
void wconv(const float* __restrict__ Wg, u16* __restrict__ wp) {
    const int G  = blockIdx.x * 256 + threadIdx.x;   // 0..16383
    const int l  = G & 63;
    const int r  = G >> 6;                           // kstep*4+etile
    const int ks = r >> 2, et = r & 3;
    const int ex = et * 16 + (l & 15);
    const int k  = ks * 32 + (l >> 4) * 8;
    const float* src = Wg + (size_t)ex * DIM + k;
    f32x4 v0 = *(const f32x4*)src;
    f32x4 v1 = *(const f32x4*)(src + 4);
    u16 h0[8], h1[8], h2[8];
#pragma unroll
    for (int i = 0; i < 8; ++i) {
        float xv = (i < 4) ? v0[i] : v1[i - 4];
        split3(xv, h0[i], h1[i], h2[i]);
    }
    u16* dst = wp + ((size_t)r * 3) * 512 + l * 8;
    *(bf16x8*)(dst)        = *(bf16x8*)h0;
    *(bf16x8*)(dst + 512)  = *(bf16x8*)h1;
    *(bf16x8*)(dst + 1024) = *(bf16x8*)h2;
}

// ---------------- Kernel 1: deep-pipelined MFMA router ----------------------
// 32 tokens/block, 8 waves = 2 tok-tiles x 4 K-interleaves; grid 512 = 2/CU.
// 4-deep LDS ring fed ONLY by global_load_lds (16 units/kstep, 2 per wave);
// raw s_barrier + counted vmcnt(4) -> 3 slots always in flight. Wave (tt,kq)
// computes ksteps c%4==kq: split3 once, 12 B ds_reads, 24 MFMAs.
__global__ __launch_bounds__(TPB, 4)
void router_main(const float* __restrict__ x, const u16* __restrict__ wp,
                 float* __restrict__ out, float* __restrict__ gCnt,
                 float* __restrict__ gPsum, int n_tokens) {
    __shared__ __align__(16) unsigned char smem[DEPTH * SLOTB];  // 64 KB
    __shared__ float cnt[NEXP];
    __shared__ float rs[TOKB];

    const int tid  = threadIdx.x;
    const int lane = tid & 63;
    const int wid  = tid >> 6;       // 0..7
    const int tt   = wid & 1;        // token-tile (active waves on distinct SIMDs)
    const int kq   = wid >> 1;       // K-interleave 0..3
    const int t0   = blockIdx.x * TOKB;

    if (tid < NEXP) cnt[tid] = 0.f;

    f32x4 acc[4];
#pragma unroll
    for (int et = 0; et < 4; ++et) acc[et] = (f32x4){0.f, 0.f, 0.f, 0.f};

    // ---- staging units for this wave: u0=2*wid, u1=2*wid+1 of 16 ----
    //   u<4:  x fragment (tt_u=u>>1, q=u&1), dst off u*1024
    //   u>=4: B fragment j=u-4,              dst off u*1024
    const int u0 = 2 * wid, u1 = 2 * wid + 1;
    const char* src0; const char* src1;
    int str0, str1;
    {
        if (u0 < 4) {
            src0 = (const char*)(x + (size_t)(t0 + 16 * (u0 >> 1) + (lane & 15)) * DIM
                                   + 8 * (lane >> 4) + 4 * (u0 & 1));
            str0 = 32 * 4;
        } else {
            src0 = (const char*)(wp + (size_t)(u0 - 4) * 512 + lane * 8);
            str0 = 12 * 512 * 2;
        }
        if (u1 < 4) {
            src1 = (const char*)(x + (size_t)(t0 + 16 * (u1 >> 1) + (lane & 15)) * DIM
                                   + 8 * (lane >> 4) + 4 * (u1 & 1));
            str1 = 32 * 4;
        } else {
            src1 = (const char*)(wp + (size_t)(u1 - 4) * 512 + lane * 8);
            str1 = 12 * 512 * 2;
        }
    }

#define ISSUE(K) do {                                                          \
        unsigned char* sl_ = smem + ((K) & 3) * SLOTB;                         \
        GLD(src0 + (size_t)(K) * str0, sl_ + u0 * 1024);                       \
        GLD(src1 + (size_t)(K) * str1, sl_ + u1 * 1024);                       \
    } while (0)

    // prologue: slots 0..2 in flight (6 loads/wave)
    ISSUE(0);
    ISSUE(1);
    ISSUE(2);

    for (int c = 0; c < NCH; ++c) {
        // own slot-c loads complete (2 slots stay in flight; never drain)
        if (c < NCH - 2) asm volatile("s_waitcnt vmcnt(4)" ::: "memory");
        else             asm volatile("s_waitcnt vmcnt(0)" ::: "memory");
        __builtin_amdgcn_s_barrier();            // everyone's slot c complete
        __builtin_amdgcn_sched_barrier(0);       // rule 18: no hoisting
        if (c + DEPTH - 1 < NCH) ISSUE(c + DEPTH - 1);  // overwrites slot read
        __builtin_amdgcn_sched_barrier(0);              // at c-1: safe post-bar
        if ((c & 3) == kq) {
            const char* sb = (const char*)smem + (c & 3) * SLOTB;
            f32x4 px0 = *(const f32x4*)(sb + tt * 2048 + lane * 16);
            f32x4 px1 = *(const f32x4*)(sb + tt * 2048 + 1024 + lane * 16);
            u16 a_[8], b_[8], c_[8];
#pragma unroll
            for (int i = 0; i < 8; ++i) {
                float f = (i < 4) ? px0[i] : px1[i - 4];
                split3(f, a_[i], b_[i], c_[i]);
            }
            bf16x8 A0 = *(bf16x8*)a_;
            bf16x8 A1 = *(bf16x8*)b_;
            bf16x8 A2 = *(bf16x8*)c_;
#pragma unroll
            for (int et = 0; et < 4; ++et) {
                const char* bp = sb + 4096 + (size_t)et * 3072;
                bf16x8 B0 = *(const bf16x8*)(bp + lane * 16);
                bf16x8 B1 = *(const bf16x8*)(bp + 1024 + lane * 16);
                bf16x8 B2 = *(const bf16x8*)(bp + 2048 + lane * 16);
                acc[et] = MFMA(A0, B0, acc[et], 0, 0, 0);
                acc[et] = MFMA(A0, B1, acc[et], 0, 0, 0);
                acc[et] = MFMA(A1, B0, acc[et], 0, 0, 0);
                acc[et] = MFMA(A1, B1, acc[et], 0, 0, 0);
                acc[et] = MFMA(A0, B2, acc[et], 0, 0, 0);
                acc[et] = MFMA(A2, B0, acc[et], 0, 0, 0);
            }
        }
    }
#undef ISSUE

    __syncthreads();   // ring dead; overlay logits scratch on it
    float (*ls)[4][16][68] = (float (*)[4][16][68])smem;   // 34.8 KB < 64 KB

    // ---- per-wave partial logits (C layout: col=lane&15, row=4*(lane>>4)+r)
    {
        const int mr = 4 * (lane >> 4);
        const int e0 = lane & 15;
#pragma unroll
        for (int r = 0; r < 4; ++r) {
            ls[tt][kq][mr + r][e0]      = acc[0][r];
            ls[tt][kq][mr + r][e0 + 16] = acc[1][r];
            ls[tt][kq][mr + r][e0 + 32] = acc[2][r];
            ls[tt][kq][mr + r][e0 + 48] = acc[3][r];
        }
    }
    __syncthreads();

    // ---- reduce 4 K-interleaves (512 threads, one f32x4 each) ----
    {
        const int rt = tid >> 8;            // token-half 0/1
        const int m  = (tid >> 4) & 15;
        const int e4 = (tid & 15) * 4;
        f32x4 v = *(const f32x4*)&ls[rt][0][m][e4];
        v = v + *(const f32x4*)&ls[rt][1][m][e4];
        v = v + *(const f32x4*)&ls[rt][2][m][e4];
        v = v + *(const f32x4*)&ls[rt][3][m][e4];
        *(f32x4*)&ls[rt][0][m][e4] = v;
    }
    __syncthreads();

    // ---- per-token top-2 + softmax: 16 threads per token ----
    const int tok = tid >> 4;           // 0..31
    const int sub = tid & 15;
    const int rt2 = tok >> 4, mm = tok & 15;
    float l4[4];
#pragma unroll
    for (int j = 0; j < 4; ++j) l4[j] = ls[rt2][0][mm][sub * 4 + j];
    float m1 = -1e30f, m2 = -1e30f;
    int   i1 = 0, i2 = 0;
#pragma unroll
    for (int j = 0; j < 4; ++j) {
        float v = l4[j]; int e = sub * 4 + j;
        if (v > m1)      { m2 = m1; i2 = i1; m1 = v; i1 = e; }
        else if (v > m2) { m2 = v; i2 = e; }
    }
#pragma unroll
    for (int off = 1; off < 16; off <<= 1) {
        float n1 = __shfl_xor(m1, off, 16); int j1 = __shfl_xor(i1, off, 16);
        float n2 = __shfl_xor(m2, off, 16); int j2 = __shfl_xor(i2, off, 16);
        bool fb = (m1 > n1) || (m1 == n1 && i1 < j1);   // ties: lower index
        float a1 = fb ? m1 : n1;  int ai = fb ? i1 : j1;
        float b1 = fb ? n1 : m1;  int bi = fb ? j1 : i1;
        float c2 = fb ? m2 : n2;  int ci = fb ? i2 : j2;
        bool bb = (b1 > c2) || (b1 == c2 && bi < ci);
        m1 = a1; i1 = ai;
        m2 = bb ? b1 : c2; i2 = bb ? bi : ci;
    }
    float psum = 0.f;
#pragma unroll
    for (int j = 0; j < 4; ++j) {
        float p = __expf(l4[j] - m1);
        psum += p;
        ls[rt2][0][mm][sub * 4 + j] = p;    // unnormalized probs
    }
#pragma unroll
    for (int off = 1; off < 16; off <<= 1) psum += __shfl_xor(psum, off, 16);
    const float inv = 1.f / psum;
    if (sub == 0) {
        rs[tok] = inv;
        const float p1 = inv;                     // exp(0)*inv
        const float p2 = __expf(m2 - m1) * inv;
        const float d  = p1 + p2 + 1e-8f;
        const int tg = blockIdx.x * TOKB + tok;
        out[(size_t)tg * 2]     = (float)i1;
        out[(size_t)tg * 2 + 1] = (float)i2;
        out[(size_t)n_tokens * 2 + (size_t)tg * 2]     = p1 / d;
        out[(size_t)n_tokens * 2 + (size_t)tg * 2 + 1] = p2 / d;
        atomicAdd(&cnt[i1], 1.f);
        atomicAdd(&cnt[i2], 1.f);
    }
    __syncthreads();

    // ---- per-expert column sums + global accumulation ----
    if (tid < NEXP) {
        float cs = 0.f;
#pragma unroll
        for (int t2 = 0; t2 < TOKB; ++t2)
            cs += ls[t2 >> 4][0][t2 & 15][tid] * rs[t2];
        atomicAdd(&gPsum[tid], cs);
        atomicAdd(&gCnt[tid], cnt[tid]);
    }
}

// ---------------- Kernel 2: final aux loss -----------------------------------
__global__ void router_aux(const float* __restrict__ gCnt,
                           const float* __restrict__ gPsum,
                           float* __restrict__ out, int n_tokens) {
    const int e = threadIdx.x;
    float f = gCnt[e] / (float)(n_tokens * 2);
    float P = gPsum[e] / (float)n_tokens;
    float v = f * P;
#pragma unroll
    for (int o = 32; o > 0; o >>= 1) v += __shfl_down(v, o);
    if (e == 0) out[(size_t)n_tokens * 4] = 64.f * v;
}

extern "C" void kernel_launch(void* const* d_in, const int* in_sizes, int n_in,
                              void* d_out, int out_size, void* d_ws, size_t ws_size,
                              hipStream_t stream) {
    const float* x  = (const float*)d_in[0];
    const float* Wg = (const float*)d_in[1];
    float* out = (float*)d_out;
    const int n_tokens = in_sizes[0] / DIM;   // 16384

    // ws layout: wplanes (256*3*512 u16 = 786 KB), then gCnt/gPsum
    u16*   wplanes = (u16*)d_ws;
    float* gCnt    = (float*)((char*)d_ws + 256 * 3 * 512 * sizeof(u16));
    float* gPsum   = gCnt + NEXP;

    hipMemsetAsync(gCnt, 0, 2 * NEXP * sizeof(float), stream);
    hipLaunchKernelGGL(wconv, dim3(64), dim3(256), 0, stream, Wg, wplanes);
    hipLaunchKernelGGL(router_main, dim3(n_tokens / TOKB), dim3(TPB), 0, stream,
                       x, wplanes, out, gCnt, gPsum, n_tokens);
    hipLaunchKernelGGL(router_aux, dim3(1), dim3(NEXP), 0, stream,
                       gCnt, gPsum, out, n_tokens);
}

// Round 16
// 70.679 us; speedup vs baseline: 1.2905x; 1.2905x over previous
//
#include <hip/hip_runtime.h>
#include <math.h>

#define DIM   2048
#define NEXP  64
#define TPB   256        // 4 waves
#define TOKB  64
#define NCH   64         // ksteps of K=32
#define PPH   4          // ksteps per phase (one 48KB half-buffer)
#define NPH   (NCH/PPH)  // 16 phases

typedef float f32x4  __attribute__((ext_vector_type(4)));
typedef short bf16x8 __attribute__((ext_vector_type(8)));
typedef unsigned short u16;

#define MFMA __builtin_amdgcn_mfma_f32_16x16x32_bf16

// ---- fp32 -> 3-term bf16 split (RNE). Error ~2^-26 relative: index-safe. ----
__device__ __forceinline__ u16 rne_bf16(float f) {
    union { float f; unsigned u; } v; v.f = f;
    unsigned u = v.u;
    u += 0x7fffu + ((u >> 16) & 1u);
    return (u16)(u >> 16);
}
__device__ __forceinline__ float bf2f(u16 h) {
    union { unsigned u; float f; } v; v.u = ((unsigned)h) << 16;
    return v.f;
}
__device__ __forceinline__ void split3(float x, u16& a, u16& b, u16& c) {
    a = rne_bf16(x);
    float r1 = x - bf2f(a);
    b = rne_bf16(r1);
    float r2 = r1 - bf2f(b);
    c = rne_bf16(r2);
}

#define GLD(GP, LP) __builtin_amdgcn_global_load_lds(                          \
        (const __attribute__((address_space(1))) unsigned*)(GP),               \
        (__attribute__((address_space(3))) unsigned*)(LP), 16, 0, 0)

// ---------------- Kernel 0: W -> 3 bf16 planes, MFMA-B-fragment-linear -------
// wp[kstep*12 + etile*3 + plane][lane][8];
// element: W[16*etile + (lane&15)][32*kstep + 8*(lane>>4) + i]
__global__ __launch_bounds__(256)
void wconv(const float* __restrict__ Wg, u16* __restrict__ wp) {
    const int G  = blockIdx.x * 256 + threadIdx.x;   // 0..16383
    const int l  = G & 63;
    const int r  = G >> 6;                           // kstep*4+etile
    const int ks = r >> 2, et = r & 3;
    const int ex = et * 16 + (l & 15);
    const int k  = ks * 32 + (l >> 4) * 8;
    const float* src = Wg + (size_t)ex * DIM + k;
    f32x4 v0 = *(const f32x4*)src;
    f32x4 v1 = *(const f32x4*)(src + 4);
    u16 h0[8], h1[8], h2[8];
#pragma unroll
    for (int i = 0; i < 8; ++i) {
        float xv = (i < 4) ? v0[i] : v1[i - 4];
        split3(xv, h0[i], h1[i], h2[i]);
    }
    u16* dst = wp + ((size_t)r * 3) * 512 + l * 8;
    *(bf16x8*)(dst)        = *(bf16x8*)h0;
    *(bf16x8*)(dst + 512)  = *(bf16x8*)h1;
    *(bf16x8*)(dst + 1024) = *(bf16x8*)h2;
}

// ---------------- Kernel 1: phase-resident-B MFMA router (fully fused) -------
// 64 tokens/block, 4 waves x 16 tokens, FULL K in-block. grid 256 = 1/CU.
// B: double-buffered 48KB halves (4 ksteps each), staged by global_load_lds
// (wave w stages kstep-slot w), ONE barrier per phase. x: per-lane direct,
// depth-2 register prefetch. Epilogue fused (no partials round-trip).
__global__ __launch_bounds__(TPB, 1)
void router_main(const float* __restrict__ x, const u16* __restrict__ wp,
                 float* __restrict__ out, float* __restrict__ gCnt,
                 float* __restrict__ gPsum, int n_tokens) {
    __shared__ __align__(16) u16 bs[2][PPH][12][512];   // 96 KB
    __shared__ float ls[TOKB][NEXP + 4];                // 17.4 KB
    __shared__ float cnt[NEXP];
    __shared__ float rs[TOKB];

    const int tid  = threadIdx.x;
    const int lane = tid & 63;
    const int w    = tid >> 6;          // wave 0..3
    const int t0   = blockIdx.x * TOKB;

    if (tid < NEXP) cnt[tid] = 0.f;

    f32x4 acc[4];
#pragma unroll
    for (int et = 0; et < 4; ++et) acc[et] = (f32x4){0.f, 0.f, 0.f, 0.f};

    // A-fragment source: token = t0+16w+(lane&15), k = 8*(lane>>4)+i (verified)
    const float* xsrc = x + (size_t)(t0 + 16 * w + (lane & 15)) * DIM + 8 * (lane >> 4);

    // wave w stages kstep-slot w of phase P (12 frag-rows of 1KB)
#define STAGEPH(P, H) do {                                                     \
        const u16* gp_ = wp + ((size_t)((P) * PPH + w) * 12) * 512 + lane * 8; \
        _Pragma("unroll")                                                      \
        for (int j = 0; j < 12; ++j)                                           \
            GLD(gp_ + (size_t)j * 512, &bs[H][w][j][0]);                       \
    } while (0)

    // depth-2 x prefetch (named sets, parity-selected with static k2)
    f32x4 pa0 = *(const f32x4*)(xsrc);
    f32x4 pa1 = *(const f32x4*)(xsrc + 4);
    f32x4 pb0 = *(const f32x4*)(xsrc + 32);
    f32x4 pb1 = *(const f32x4*)(xsrc + 36);

    STAGEPH(0, 0);
    __syncthreads();

    for (int p = 0; p < NPH; ++p) {
        const int cur = p & 1;
        if (p + 1 < NPH) STAGEPH(p + 1, cur ^ 1);   // issue next half DMA
#pragma unroll
        for (int k2 = 0; k2 < PPH; ++k2) {
            const int c = p * PPH + k2;
            f32x4 x0 = (k2 & 1) ? pb0 : pa0;
            f32x4 x1 = (k2 & 1) ? pb1 : pa1;
            if (c + 2 < NCH) {                       // reload this set (c+2)
                const float* np_ = xsrc + (size_t)(c + 2) * 32;
                if (k2 & 1) { pb0 = *(const f32x4*)np_; pb1 = *(const f32x4*)(np_ + 4); }
                else        { pa0 = *(const f32x4*)np_; pa1 = *(const f32x4*)(np_ + 4); }
            }
            u16 a_[8], b_[8], c_[8];
#pragma unroll
            for (int i = 0; i < 8; ++i) {
                float f = (i < 4) ? x0[i] : x1[i - 4];
                split3(f, a_[i], b_[i], c_[i]);
            }
            bf16x8 A0 = *(bf16x8*)a_;
            bf16x8 A1 = *(bf16x8*)b_;
            bf16x8 A2 = *(bf16x8*)c_;
#pragma unroll
            for (int et = 0; et < 4; ++et) {
                bf16x8 B0 = *(const bf16x8*)&bs[cur][k2][et * 3 + 0][lane * 8];
                bf16x8 B1 = *(const bf16x8*)&bs[cur][k2][et * 3 + 1][lane * 8];
                bf16x8 B2 = *(const bf16x8*)&bs[cur][k2][et * 3 + 2][lane * 8];
                acc[et] = MFMA(A0, B0, acc[et], 0, 0, 0);
                acc[et] = MFMA(A0, B1, acc[et], 0, 0, 0);
                acc[et] = MFMA(A1, B0, acc[et], 0, 0, 0);
                acc[et] = MFMA(A1, B1, acc[et], 0, 0, 0);
                acc[et] = MFMA(A0, B2, acc[et], 0, 0, 0);
                acc[et] = MFMA(A2, B0, acc[et], 0, 0, 0);
            }
        }
        __syncthreads();   // next half staged & visible; prev half reads done
    }
#undef STAGEPH

    // ---- logits -> LDS (C layout: col=lane&15, row=4*(lane>>4)+r, verified)
    {
        const int mr = 16 * w + 4 * (lane >> 4);
        const int e0 = lane & 15;
#pragma unroll
        for (int r = 0; r < 4; ++r) {
            ls[mr + r][e0]      = acc[0][r];
            ls[mr + r][e0 + 16] = acc[1][r];
            ls[mr + r][e0 + 32] = acc[2][r];
            ls[mr + r][e0 + 48] = acc[3][r];
        }
    }
    __syncthreads();

    // ---- per-token top-2 + softmax: 4 threads per token ----
    const int tok = tid >> 2;           // 0..63
    const int sub = tid & 3;
    float l16[16];
#pragma unroll
    for (int j = 0; j < 16; ++j) l16[j] = ls[tok][sub * 16 + j];
    float m1 = -1e30f, m2 = -1e30f;
    int   i1 = 0, i2 = 0;
#pragma unroll
    for (int j = 0; j < 16; ++j) {
        float v = l16[j]; int e = sub * 16 + j;
        if (v > m1)      { m2 = m1; i2 = i1; m1 = v; i1 = e; }
        else if (v > m2) { m2 = v; i2 = e; }
    }
#pragma unroll
    for (int off = 1; off < 4; off <<= 1) {
        float n1 = __shfl_xor(m1, off, 4); int j1 = __shfl_xor(i1, off, 4);
        float n2 = __shfl_xor(m2, off, 4); int j2 = __shfl_xor(i2, off, 4);
        bool fb = (m1 > n1) || (m1 == n1 && i1 < j1);   // ties: lower index
        float a1 = fb ? m1 : n1;  int ai = fb ? i1 : j1;
        float b1 = fb ? n1 : m1;  int bi = fb ? j1 : i1;
        float c2 = fb ? m2 : n2;  int ci = fb ? i2 : j2;
        bool bb = (b1 > c2) || (b1 == c2 && bi < ci);
        m1 = a1; i1 = ai;
        m2 = bb ? b1 : c2; i2 = bb ? bi : ci;
    }
    float psum = 0.f;
#pragma unroll
    for (int j = 0; j < 16; ++j) {
        float pv = __expf(l16[j] - m1);
        psum += pv;
        ls[tok][sub * 16 + j] = pv;     // unnormalized probs
    }
#pragma unroll
    for (int off = 1; off < 4; off <<= 1) psum += __shfl_xor(psum, off, 4);
    const float inv = 1.f / psum;
    if (sub == 0) {
        rs[tok] = inv;
        const float p1 = inv;                     // exp(0)*inv
        const float p2 = __expf(m2 - m1) * inv;
        const float d  = p1 + p2 + 1e-8f;
        const int tg = t0 + tok;
        out[(size_t)tg * 2]     = (float)i1;
        out[(size_t)tg * 2 + 1] = (float)i2;
        out[(size_t)n_tokens * 2 + (size_t)tg * 2]     = p1 / d;
        out[(size_t)n_tokens * 2 + (size_t)tg * 2 + 1] = p2 / d;
        atomicAdd(&cnt[i1], 1.f);
        atomicAdd(&cnt[i2], 1.f);
    }
    __syncthreads();

    // ---- per-expert column sums + global accumulation ----
    if (tid < NEXP) {
        float cs = 0.f;
#pragma unroll 8
        for (int t = 0; t < TOKB; ++t) cs += ls[t][tid] * rs[t];
        atomicAdd(&gPsum[tid], cs);
        atomicAdd(&gCnt[tid], cnt[tid]);
    }
}

// ---------------- Kernel 2: final aux loss -----------------------------------
__global__ void router_aux(const float* __restrict__ gCnt,
                           const float* __restrict__ gPsum,
                           float* __restrict__ out, int n_tokens) {
    const int e = threadIdx.x;
    float f = gCnt[e] / (float)(n_tokens * 2);
    float P = gPsum[e] / (float)n_tokens;
    float v = f * P;
#pragma unroll
    for (int o = 32; o > 0; o >>= 1) v += __shfl_down(v, o);
    if (e == 0) out[(size_t)n_tokens * 4] = 64.f * v;
}

extern "C" void kernel_launch(void* const* d_in, const int* in_sizes, int n_in,
                              void* d_out, int out_size, void* d_ws, size_t ws_size,
                              hipStream_t stream) {
    const float* x  = (const float*)d_in[0];
    const float* Wg = (const float*)d_in[1];
    float* out = (float*)d_out;
    const int n_tokens = in_sizes[0] / DIM;   // 16384

    // ws layout: wplanes (256*3*512 u16 = 786 KB), then gCnt/gPsum
    u16*   wplanes = (u16*)d_ws;
    float* gCnt    = (float*)((char*)d_ws + 256 * 3 * 512 * sizeof(u16));
    float* gPsum   = gCnt + NEXP;

    hipMemsetAsync(gCnt, 0, 2 * NEXP * sizeof(float), stream);
    hipLaunchKernelGGL(wconv, dim3(64), dim3(256), 0, stream, Wg, wplanes);
    hipLaunchKernelGGL(router_main, dim3(n_tokens / TOKB), dim3(TPB), 0, stream,
                       x, wplanes, out, gCnt, gPsum, n_tokens);
    hipLaunchKernelGGL(router_aux, dim3(1), dim3(NEXP), 0, stream,
                       gCnt, gPsum, out, n_tokens);
}

// Round 17
// 54.486 us; speedup vs baseline: 1.6741x; 1.2972x over previous
//
#include <hip/hip_runtime.h>
#include <math.h>

#define DIM   2048
#define NEXP  64
#define TPB   512
#define TOKB  64
#define KSQ   16         // ksteps (K=32) per K-quarter

typedef float f32x4  __attribute__((ext_vector_type(4)));
typedef short bf16x8 __attribute__((ext_vector_type(8)));
typedef unsigned short u16;

#define MFMA __builtin_amdgcn_mfma_f32_16x16x32_bf16

// ---- software RNE bf16 (wconv only) ----
__device__ __forceinline__ u16 rne_bf16(float f) {
    union { float f; unsigned u; } v; v.f = f;
    unsigned u = v.u;
    u += 0x7fffu + ((u >> 16) & 1u);
    return (u16)(u >> 16);
}
__device__ __forceinline__ float bf2f(u16 h) {
    union { unsigned u; float f; } v; v.u = ((unsigned)h) << 16;
    return v.f;
}
__device__ __forceinline__ void split3(float x, u16& a, u16& b, u16& c) {
    a = rne_bf16(x);
    float r1 = x - bf2f(a);
    b = rne_bf16(r1);
    float r2 = r1 - bf2f(b);
    c = rne_bf16(r2);
}

// ---- hw packed cvt: D = {bf16(lo), bf16(hi)} in one instruction ----
__device__ __forceinline__ unsigned cvt_pk(float lo, float hi) {
    unsigned r;
    asm("v_cvt_pk_bf16_f32 %0, %1, %2" : "=v"(r) : "v"(lo), "v"(hi));
    return r;
}
__device__ __forceinline__ float lof(unsigned u) {
    union { unsigned u; float f; } v; v.u = u << 16;
    return v.f;
}
__device__ __forceinline__ float hif(unsigned u) {
    union { unsigned u; float f; } v; v.u = u & 0xffff0000u;
    return v.f;
}

// 8 floats -> 3 bf16x8 planes (3-term split, err ~2^-25: index-safe)
__device__ __forceinline__ void split3x8(f32x4 lo, f32x4 hi,
                                         bf16x8* A0, bf16x8* A1, bf16x8* A2) {
    unsigned w0[4], w1[4], w2[4];
    float e0[4] = {lo.x, lo.z, hi.x, hi.z};
    float e1[4] = {lo.y, lo.w, hi.y, hi.w};
#pragma unroll
    for (int j = 0; j < 4; ++j) {
        float a = e0[j], b = e1[j];
        unsigned p0 = cvt_pk(a, b);
        float r0 = a - lof(p0), r1 = b - hif(p0);
        unsigned p1 = cvt_pk(r0, r1);
        float s0 = r0 - lof(p1), s1 = r1 - hif(p1);
        w0[j] = p0; w1[j] = p1; w2[j] = cvt_pk(s0, s1);
    }
    *A0 = *(bf16x8*)w0;
    *A1 = *(bf16x8*)w1;
    *A2 = *(bf16x8*)w2;
}

#define GLD(GP, LP) __builtin_amdgcn_global_load_lds(                          \
        (const __attribute__((address_space(1))) unsigned*)(GP),               \
        (__attribute__((address_space(3))) unsigned*)(LP), 16, 0, 0)

// ---------------- Kernel 0: W -> 3 bf16 planes, MFMA-B-fragment-linear -------
// wp[kstep*12 + etile*3 + plane][lane][8];
// element: W[16*etile + (lane&15)][32*kstep + 8*(lane>>4) + i]
__global__ __launch_bounds__(256)
void wconv(const float* __restrict__ Wg, u16* __restrict__ wp) {
    const int G  = blockIdx.x * 256 + threadIdx.x;   // 0..16383
    const int l  = G & 63;
    const int r  = G >> 6;                           // kstep*4+etile
    const int ks = r >> 2, et = r & 3;
    const int ex = et * 16 + (l & 15);
    const int k  = ks * 32 + (l >> 4) * 8;
    const float* src = Wg + (size_t)ex * DIM + k;
    f32x4 v0 = *(const f32x4*)src;
    f32x4 v1 = *(const f32x4*)(src + 4);
    u16 h0[8], h1[8], h2[8];
#pragma unroll
    for (int i = 0; i < 8; ++i) {
        float xv = (i < 4) ? v0[i] : v1[i - 4];
        split3(xv, h0[i], h1[i], h2[i]);
    }
    u16* dst = wp + ((size_t)(ks * 12 + et * 3)) * 512 + l * 8;
    *(bf16x8*)(dst)        = *(bf16x8*)h0;
    *(bf16x8*)(dst + 512)  = *(bf16x8*)h1;
    *(bf16x8*)(dst + 1024) = *(bf16x8*)h2;
}

// ---------------- Kernel 1: 2-tile-per-wave MFMA router (fully fused) --------
// 64 tokens/block, 8 waves = 2 token-groups(32 tok) x 4 K-quarters(512).
// grid 256 = 1 block/CU = 2 waves/SIMD. Each wave: 2 A-tiles share one set of
// 12 B ds_reads -> 48 MFMA / kstep. B per-quarter double-buffered via
// global_load_lds; ONE __syncthreads per kstep (16 total; drain covered).
__global__ __launch_bounds__(TPB, 2)
void router_main(const float* __restrict__ x, const u16* __restrict__ wp,
                 float* __restrict__ out, float* __restrict__ gCnt,
                 float* __restrict__ gPsum, int n_tokens) {
    __shared__ __align__(16) unsigned char smem[4 * 2 * 12 * 1024]; // 96 KB
    __shared__ float cnt[NEXP];
    __shared__ float rs[TOKB];
    u16 (*bq)[2][12][512] = (u16 (*)[2][12][512])smem;   // [kq][buf][frag][lane*8]
    float (*ls)[TOKB][68] = (float (*)[TOKB][68])smem;   // epilogue overlay 69.6KB

    const int tid  = threadIdx.x;
    const int lane = tid & 63;
    const int wid  = tid >> 6;       // 0..7
    const int ttg  = wid & 1;        // token-group (32 tokens)
    const int kq   = wid >> 1;       // K-quarter 0..3
    const int t0   = blockIdx.x * TOKB;

    if (tid < NEXP) cnt[tid] = 0.f;

    f32x4 acc[2][4];
#pragma unroll
    for (int t2 = 0; t2 < 2; ++t2)
#pragma unroll
        for (int et = 0; et < 4; ++et) acc[t2][et] = (f32x4){0.f, 0.f, 0.f, 0.f};

    // A sources: tile t2 token row = t0 + 32*ttg + 16*t2 + (lane&15)
    const float* xs0 = x + (size_t)(t0 + 32 * ttg + (lane & 15)) * DIM
                         + kq * (KSQ * 32) + 8 * (lane >> 4);
    const float* xs1 = xs0 + (size_t)16 * DIM;

    // wave stages frags [6*ttg, 6*ttg+6) of its quarter's next kstep
#define STAGEB(C) do {                                                         \
        const int g_ = kq * KSQ + (C);                                         \
        const u16* gp_ = wp + ((size_t)g_ * 12 + 6 * ttg) * 512 + lane * 8;    \
        _Pragma("unroll")                                                      \
        for (int f = 0; f < 6; ++f)                                            \
            GLD(gp_ + (size_t)f * 512, &bq[kq][(C) & 1][6 * ttg + f][0]);      \
    } while (0)

#define LOADX(S0, S1, S2, S3, C) do {                                          \
        S0 = *(const f32x4*)(xs0 + (C) * 32);                                  \
        S1 = *(const f32x4*)(xs0 + (C) * 32 + 4);                              \
        S2 = *(const f32x4*)(xs1 + (C) * 32);                                  \
        S3 = *(const f32x4*)(xs1 + (C) * 32 + 4);                              \
    } while (0)

#define ITER(C, S0, S1, S2, S3) do {                                           \
        if ((C) + 1 < KSQ) STAGEB((C) + 1);                                    \
        bf16x8 A00, A01, A02, A10, A11, A12;                                   \
        split3x8(S0, S1, &A00, &A01, &A02);                                    \
        split3x8(S2, S3, &A10, &A11, &A12);                                    \
        if ((C) + 2 < KSQ) LOADX(S0, S1, S2, S3, (C) + 2);                     \
        _Pragma("unroll")                                                      \
        for (int et = 0; et < 4; ++et) {                                       \
            bf16x8 B0 = *(const bf16x8*)&bq[kq][(C) & 1][et * 3 + 0][lane * 8];\
            bf16x8 B1 = *(const bf16x8*)&bq[kq][(C) & 1][et * 3 + 1][lane * 8];\
            bf16x8 B2 = *(const bf16x8*)&bq[kq][(C) & 1][et * 3 + 2][lane * 8];\
            acc[0][et] = MFMA(A00, B0, acc[0][et], 0, 0, 0);                   \
            acc[0][et] = MFMA(A00, B1, acc[0][et], 0, 0, 0);                   \
            acc[0][et] = MFMA(A01, B0, acc[0][et], 0, 0, 0);                   \
            acc[0][et] = MFMA(A01, B1, acc[0][et], 0, 0, 0);                   \
            acc[0][et] = MFMA(A00, B2, acc[0][et], 0, 0, 0);                   \
            acc[0][et] = MFMA(A02, B0, acc[0][et], 0, 0, 0);                   \
            acc[1][et] = MFMA(A10, B0, acc[1][et], 0, 0, 0);                   \
            acc[1][et] = MFMA(A10, B1, acc[1][et], 0, 0, 0);                   \
            acc[1][et] = MFMA(A11, B0, acc[1][et], 0, 0, 0);                   \
            acc[1][et] = MFMA(A11, B1, acc[1][et], 0, 0, 0);                   \
            acc[1][et] = MFMA(A10, B2, acc[1][et], 0, 0, 0);                   \
            acc[1][et] = MFMA(A12, B0, acc[1][et], 0, 0, 0);                   \
        }                                                                      \
        __syncthreads();                                                       \
    } while (0)

    f32x4 pa0, pa1, pa2, pa3, pb0, pb1, pb2, pb3;
    STAGEB(0);
    LOADX(pa0, pa1, pa2, pa3, 0);
    LOADX(pb0, pb1, pb2, pb3, 1);
    __syncthreads();                 // drain: kstep-0 B staged & visible

    for (int cc = 0; cc < KSQ; cc += 2) {
        ITER(cc,     pa0, pa1, pa2, pa3);
        ITER(cc + 1, pb0, pb1, pb2, pb3);
    }
#undef ITER
#undef LOADX
#undef STAGEB

    // ---- partial logits -> overlay LDS (C layout verified: col=lane&15,
    //      row=4*(lane>>4)+r), indexed by K-quarter for the reduce
    {
        const int e0 = lane & 15;
#pragma unroll
        for (int t2 = 0; t2 < 2; ++t2) {
            const int mr = 32 * ttg + 16 * t2 + 4 * (lane >> 4);
#pragma unroll
            for (int r = 0; r < 4; ++r) {
                ls[kq][mr + r][e0]      = acc[t2][0][r];
                ls[kq][mr + r][e0 + 16] = acc[t2][1][r];
                ls[kq][mr + r][e0 + 32] = acc[t2][2][r];
                ls[kq][mr + r][e0 + 48] = acc[t2][3][r];
            }
        }
    }
    __syncthreads();

    // ---- reduce 4 K-quarters (512 threads x 2 f32x4) ----
#pragma unroll
    for (int r2 = 0; r2 < 2; ++r2) {
        const int idx = tid + TPB * r2;     // 0..1023
        const int tk  = idx >> 4;           // 0..63
        const int e4  = (idx & 15) * 4;
        f32x4 v = *(const f32x4*)&ls[0][tk][e4];
        v = v + *(const f32x4*)&ls[1][tk][e4];
        v = v + *(const f32x4*)&ls[2][tk][e4];
        v = v + *(const f32x4*)&ls[3][tk][e4];
        *(f32x4*)&ls[0][tk][e4] = v;
    }
    __syncthreads();

    // ---- per-token top-2 + softmax: 8 threads per token ----
    const int tok = tid >> 3;           // 0..63
    const int sub = tid & 7;
    float l8[8];
#pragma unroll
    for (int j = 0; j < 8; ++j) l8[j] = ls[0][tok][sub * 8 + j];
    float m1 = -1e30f, m2 = -1e30f;
    int   i1 = 0, i2 = 0;
#pragma unroll
    for (int j = 0; j < 8; ++j) {
        float v = l8[j]; int e = sub * 8 + j;
        if (v > m1)      { m2 = m1; i2 = i1; m1 = v; i1 = e; }
        else if (v > m2) { m2 = v; i2 = e; }
    }
#pragma unroll
    for (int off = 1; off < 8; off <<= 1) {
        float n1 = __shfl_xor(m1, off, 8); int j1 = __shfl_xor(i1, off, 8);
        float n2 = __shfl_xor(m2, off, 8); int j2 = __shfl_xor(i2, off, 8);
        bool fb = (m1 > n1) || (m1 == n1 && i1 < j1);   // ties: lower index
        float a1 = fb ? m1 : n1;  int ai = fb ? i1 : j1;
        float b1 = fb ? n1 : m1;  int bi = fb ? j1 : i1;
        float c2 = fb ? m2 : n2;  int ci = fb ? i2 : j2;
        bool bb = (b1 > c2) || (b1 == c2 && bi < ci);
        m1 = a1; i1 = ai;
        m2 = bb ? b1 : c2; i2 = bb ? bi : ci;
    }
    float psum = 0.f;
#pragma unroll
    for (int j = 0; j < 8; ++j) {
        float p = __expf(l8[j] - m1);
        psum += p;
        ls[0][tok][sub * 8 + j] = p;    // unnormalized probs
    }
#pragma unroll
    for (int off = 1; off < 8; off <<= 1) psum += __shfl_xor(psum, off, 8);
    const float inv = 1.f / psum;
    if (sub == 0) {
        rs[tok] = inv;
        const float p1 = inv;                     // exp(0)*inv
        const float p2 = __expf(m2 - m1) * inv;
        const float d  = p1 + p2 + 1e-8f;
        const int tg = t0 + tok;
        out[(size_t)tg * 2]     = (float)i1;
        out[(size_t)tg * 2 + 1] = (float)i2;
        out[(size_t)n_tokens * 2 + (size_t)tg * 2]     = p1 / d;
        out[(size_t)n_tokens * 2 + (size_t)tg * 2 + 1] = p2 / d;
        atomicAdd(&cnt[i1], 1.f);
        atomicAdd(&cnt[i2], 1.f);
    }
    __syncthreads();

    // ---- per-expert column sums + global accumulation ----
    if (tid < NEXP) {
        float cs = 0.f;
#pragma unroll 8
        for (int t = 0; t < TOKB; ++t) cs += ls[0][t][tid] * rs[t];
        atomicAdd(&gPsum[tid], cs);
        atomicAdd(&gCnt[tid], cnt[tid]);
    }
}

// ---------------- Kernel 2: final aux loss -----------------------------------
__global__ void router_aux(const float* __restrict__ gCnt,
                           const float* __restrict__ gPsum,
                           float* __restrict__ out, int n_tokens) {
    const int e = threadIdx.x;
    float f = gCnt[e] / (float)(n_tokens * 2);
    float P = gPsum[e] / (float)n_tokens;
    float v = f * P;
#pragma unroll
    for (int o = 32; o > 0; o >>= 1) v += __shfl_down(v, o);
    if (e == 0) out[(size_t)n_tokens * 4] = 64.f * v;
}

extern "C" void kernel_launch(void* const* d_in, const int* in_sizes, int n_in,
                              void* d_out, int out_size, void* d_ws, size_t ws_size,
                              hipStream_t stream) {
    const float* x  = (const float*)d_in[0];
    const float* Wg = (const float*)d_in[1];
    float* out = (float*)d_out;
    const int n_tokens = in_sizes[0] / DIM;   // 16384

    // ws layout: wplanes (256*3*512 u16 = 786 KB), then gCnt/gPsum
    u16*   wplanes = (u16*)d_ws;
    float* gCnt    = (float*)((char*)d_ws + 256 * 3 * 512 * sizeof(u16));
    float* gPsum   = gCnt + NEXP;

    hipMemsetAsync(gCnt, 0, 2 * NEXP * sizeof(float), stream);
    hipLaunchKernelGGL(wconv, dim3(64), dim3(256), 0, stream, Wg, wplanes);
    hipLaunchKernelGGL(router_main, dim3(n_tokens / TOKB), dim3(TPB), 0, stream,
                       x, wplanes, out, gCnt, gPsum, n_tokens);
    hipLaunchKernelGGL(router_aux, dim3(1), dim3(NEXP), 0, stream,
                       gCnt, gPsum, out, n_tokens);
}